// Round 6
// baseline (2228.892 us; speedup 1.0000x reference)
//
#include <hip/hip_runtime.h>
#include <hip/hip_bf16.h>

// THLSTM cell fused, MI355X gfx950 — round 6.
// BT=128 rows/WG, 8 waves, wave tile = 64 rows x 64 cols (4 accs, B amortized
// 4 MFMAs per B-load pair). LDS 160KB: 96KB bf16 [h|x] + 64KB bf16 s-tile.
// B-ring depth 4, A-ring depth 2. launch_bounds(512,2) — the known no-spill
// budget (256 regs total); occupancy forcing spills (rounds 4/5 evidence).

constexpr int Btot = 65536;
constexpr int H    = 256;
constexpr int I    = 128;
constexpr int BT   = 128;
constexpr int NTHR = 512;
constexpr int HXREG = 24576;    // per-32-row hx region: 48 k8 x 32 x 16B
constexpr int SOFF  = 98304;    // s-tile base (after 4 hx regions)
constexpr int SREG  = 16384;    // per-32-row s region: 32 k8 x 32 x 16B

typedef __bf16 bf16x8  __attribute__((ext_vector_type(8)));
typedef float  f32x16  __attribute__((ext_vector_type(16)));
typedef unsigned short ushort8 __attribute__((ext_vector_type(8)));

__device__ __forceinline__ unsigned short f2bf(float f) {
    unsigned u = __builtin_bit_cast(unsigned, f);
    u += 0x7fffu + ((u >> 16) & 1u);   // RNE
    return (unsigned short)(u >> 16);
}
__device__ __forceinline__ float bf2f(unsigned short s) {
    return __builtin_bit_cast(float, ((unsigned)s) << 16);
}
__device__ __forceinline__ float sigm(float x) {
    return __builtin_amdgcn_rcpf(1.0f + exp2f(-1.4426950408889634f * x));
}
__device__ __forceinline__ float tanh_f(float x) {
    return 1.0f - 2.0f * __builtin_amdgcn_rcpf(1.0f + exp2f(2.8853900817779268f * x));
}

// Weights bf16, layout [k8][col(256)][8]: elem (col, k=k8*8+e) at (k8*256+col)*8+e.
// w0: 48 k8 (gate s, K=384); wgb: 5 x 48 k8 (f,i,T,u,o hx-part);
// wsb: 5 x 32 k8 (f,i,T,u,o s-part, K=256).
__global__ void convert_w(const float* __restrict__ Wh, const float* __restrict__ Wx,
                          const float* __restrict__ Ws, unsigned short* __restrict__ w0,
                          unsigned short* __restrict__ wgb, unsigned short* __restrict__ wsb) {
    const int t  = blockIdx.x * blockDim.x + threadIdx.x;
    const int N0 = 48 * 2048;          // 98304
    const int N1 = 5 * 48 * 2048;      // 491520
    const int N2 = 5 * 32 * 2048;      // 327680
    if (t < N0) {
        const int k8 = t >> 11, rem = t & 2047;
        const int col = rem >> 3, e = rem & 7;
        const int k = k8 * 8 + e;
        const float v = (k < H) ? Wh[col * H + k] : Wx[col * I + (k - H)];
        w0[t] = f2bf(v);
    } else if (t < N0 + N1) {
        const int u   = t - N0;
        const int g1  = u / 98304;
        const int rem = u - g1 * 98304;
        const int k8  = rem >> 11;
        const int col = (rem & 2047) >> 3, e = rem & 7;
        const int k   = k8 * 8 + e;
        const int g   = g1 + 1;
        const float v = (k < H) ? Wh[g * H * H + col * H + k]
                                : Wx[g * H * I + col * I + (k - H)];
        wgb[u] = f2bf(v);
    } else if (t < N0 + N1 + N2) {
        const int u   = t - N0 - N1;
        const int g1  = u >> 16;
        const int rem = u & 65535;
        const int k8  = rem >> 11;
        const int col = (rem & 2047) >> 3, e = rem & 7;
        wsb[u] = f2bf(Ws[g1 * H * H + col * H + k8 * 8 + e]);
    }
}

// 2 A streams (row regions) x 2 B streams (col tiles) -> 4 MFMAs/iter.
// B-ring depth 4, A-ring depth 2, fully static indexing.
template<int NIT>
__device__ __forceinline__ void gemm4(const unsigned char* Ab, int a0off, int a1off,
        const unsigned short* __restrict__ Wp,
        f32x16& c00, f32x16& c01, f32x16& c10, f32x16& c11) {
    bf16x8 br0[4], br1[4], ar0[2], ar1[2];
    #pragma unroll
    for (int i = 0; i < 4; ++i) {
        br0[i] = *(const bf16x8*)(Wp + i * 4096);
        br1[i] = *(const bf16x8*)(Wp + i * 4096 + 256);
    }
    #pragma unroll
    for (int i = 0; i < 2; ++i) {
        ar0[i] = *(const bf16x8*)(Ab + a0off + i * 1024);
        ar1[i] = *(const bf16x8*)(Ab + a1off + i * 1024);
    }
    #pragma unroll
    for (int i = 0; i < NIT; ++i) {
        const bf16x8 av0 = ar0[i & 1], av1 = ar1[i & 1];
        const bf16x8 bv0 = br0[i & 3], bv1 = br1[i & 3];
        if (i + 2 < NIT) {
            ar0[i & 1] = *(const bf16x8*)(Ab + a0off + (i + 2) * 1024);
            ar1[i & 1] = *(const bf16x8*)(Ab + a1off + (i + 2) * 1024);
        }
        if (i + 4 < NIT) {
            br0[i & 3] = *(const bf16x8*)(Wp + (i + 4) * 4096);
            br1[i & 3] = *(const bf16x8*)(Wp + (i + 4) * 4096 + 256);
        }
        c00 = __builtin_amdgcn_mfma_f32_32x32x16_bf16(av0, bv0, c00, 0, 0, 0);
        c01 = __builtin_amdgcn_mfma_f32_32x32x16_bf16(av0, bv1, c01, 0, 0, 0);
        c10 = __builtin_amdgcn_mfma_f32_32x32x16_bf16(av1, bv0, c10, 0, 0, 0);
        c11 = __builtin_amdgcn_mfma_f32_32x32x16_bf16(av1, bv1, c11, 0, 0, 0);
    }
}

__global__ __launch_bounds__(NTHR, 2) void thlstm_fused(
        const float* __restrict__ x_t, const float* __restrict__ delta_t,
        const float* __restrict__ h_prev, const float* __restrict__ c_prev,
        const float* __restrict__ Wst, const float* __restrict__ bias,
        const unsigned short* __restrict__ w0, const unsigned short* __restrict__ wgb,
        const unsigned short* __restrict__ wsb, float* __restrict__ out) {
    __shared__ __align__(16) unsigned char Abuf[163840];   // 96KB hx + 64KB s
    const int tid = threadIdx.x;
    const int b0  = blockIdx.x * BT;

    // ---- stage h|x bf16, fragment order: region(row>>5), chunk (k8, row&31) ----
    #pragma unroll
    for (int it = 0; it < 12; ++it) {
        const int c   = it * NTHR + tid;
        const int k8  = c >> 7, row = c & 127;
        const float* src = (k8 < 32) ? (h_prev + (size_t)(b0 + row) * H + k8 * 8)
                                     : (x_t    + (size_t)(b0 + row) * I + (k8 - 32) * 8);
        const float4 v0 = ((const float4*)src)[0];
        const float4 v1 = ((const float4*)src)[1];
        ushort8 p;
        p[0] = f2bf(v0.x); p[1] = f2bf(v0.y); p[2] = f2bf(v0.z); p[3] = f2bf(v0.w);
        p[4] = f2bf(v1.x); p[5] = f2bf(v1.y); p[6] = f2bf(v1.z); p[7] = f2bf(v1.w);
        *(ushort8*)(Abuf + (row >> 5) * HXREG + (k8 * 32 + (row & 31)) * 16) = p;
    }
    __syncthreads();

    const int lane  = tid & 63;
    const int wv    = tid >> 6;
    const int half  = lane >> 5;
    const int l31   = lane & 31;
    const int wr    = wv >> 2;            // row half of wave: rows wr*64..wr*64+63
    const int wc    = wv & 3;             // col quarter: cols wc*64..wc*64+63
    const int rbase = 4 * half;
    const int aoff  = half * 512 + l31 * 16;
    const int a0    = (2 * wr) * HXREG + aoff;
    const int a1    = a0 + HXREG;
    const int s0    = SOFF + (2 * wr) * SREG + aoff;
    const int s1    = s0 + SREG;
    const int wb    = half * 2048 + (wc * 64 + l31) * 8;   // B base, shorts

    unsigned spk[2][2][8];   // this thread's s values, packed bf16

    // ---- gate s: K=384 over hx ----
    {
        f32x16 ac[2][2];
        #pragma unroll
        for (int q = 0; q < 2; ++q)
            #pragma unroll
            for (int p = 0; p < 2; ++p)
                #pragma unroll
                for (int r = 0; r < 16; ++r) ac[q][p][r] = 0.f;
        gemm4<24>(Abuf, a0, a1, w0 + wb, ac[0][0], ac[0][1], ac[1][0], ac[1][1]);
        #pragma unroll
        for (int ct = 0; ct < 2; ++ct) {
            const int col = wc * 64 + ct * 32 + l31;
            const float wst = Wst[col];
            const float bs  = bias[col];
            #pragma unroll
            for (int rt = 0; rt < 2; ++rt) {
                float prev = 0.f;
                #pragma unroll
                for (int r = 0; r < 16; ++r) {
                    const int grow = wr * 64 + rt * 32 + (r & 3) + 8 * (r >> 2) + rbase;
                    const float sv = tanh_f(ac[rt][ct][r] + delta_t[b0 + grow] * wst + bs);
                    *(unsigned short*)(Abuf + SOFF + (grow >> 5) * SREG +
                        ((col >> 3) * 32 + (grow & 31)) * 16 + (col & 7) * 2) = f2bf(sv);
                    if ((r & 1) == 0) prev = sv;
                    else spk[rt][ct][r >> 1] = (unsigned)f2bf(prev) | ((unsigned)f2bf(sv) << 16);
                }
            }
        }
    }
    __syncthreads();

    float cacc[2][2][16];

    // ---- gate f (wgb 0, bias 1): c = f * c_prev ----
    {
        f32x16 ac[2][2];
        #pragma unroll
        for (int q = 0; q < 2; ++q)
            #pragma unroll
            for (int p = 0; p < 2; ++p)
                #pragma unroll
                for (int r = 0; r < 16; ++r) ac[q][p][r] = 0.f;
        gemm4<24>(Abuf, a0, a1, wgb + 0 * 98304 + wb, ac[0][0], ac[0][1], ac[1][0], ac[1][1]);
        gemm4<16>(Abuf, s0, s1, wsb + 0 * 65536 + wb, ac[0][0], ac[0][1], ac[1][0], ac[1][1]);
        #pragma unroll
        for (int ct = 0; ct < 2; ++ct) {
            const int col = wc * 64 + ct * 32 + l31;
            const float bg = bias[1 * H + col];
            #pragma unroll
            for (int rt = 0; rt < 2; ++rt)
                #pragma unroll
                for (int r = 0; r < 16; ++r) {
                    const int grow = wr * 64 + rt * 32 + (r & 3) + 8 * (r >> 2) + rbase;
                    const size_t idx = (size_t)(b0 + grow) * H + col;
                    cacc[rt][ct][r] = sigm(ac[rt][ct][r] + bg) * c_prev[idx];
                }
        }
    }
    // ---- gate T (wgb 2, bias 3): c += T * s (s from regs) ----
    {
        f32x16 ac[2][2];
        #pragma unroll
        for (int q = 0; q < 2; ++q)
            #pragma unroll
            for (int p = 0; p < 2; ++p)
                #pragma unroll
                for (int r = 0; r < 16; ++r) ac[q][p][r] = 0.f;
        gemm4<24>(Abuf, a0, a1, wgb + 2 * 98304 + wb, ac[0][0], ac[0][1], ac[1][0], ac[1][1]);
        gemm4<16>(Abuf, s0, s1, wsb + 2 * 65536 + wb, ac[0][0], ac[0][1], ac[1][0], ac[1][1]);
        #pragma unroll
        for (int ct = 0; ct < 2; ++ct) {
            const int col = wc * 64 + ct * 32 + l31;
            const float bg = bias[3 * H + col];
            #pragma unroll
            for (int rt = 0; rt < 2; ++rt)
                #pragma unroll
                for (int r = 0; r < 16; ++r) {
                    const float sv = bf2f((unsigned short)((spk[rt][ct][r >> 1] >> ((r & 1) * 16)) & 0xffffu));
                    cacc[rt][ct][r] += sigm(ac[rt][ct][r] + bg) * sv;
                }
        }
    }
    unsigned ipk[2][2][8];
    // ---- gate i (wgb 1, bias 2): pack sigm(i) ----
    {
        f32x16 ac[2][2];
        #pragma unroll
        for (int q = 0; q < 2; ++q)
            #pragma unroll
            for (int p = 0; p < 2; ++p)
                #pragma unroll
                for (int r = 0; r < 16; ++r) ac[q][p][r] = 0.f;
        gemm4<24>(Abuf, a0, a1, wgb + 1 * 98304 + wb, ac[0][0], ac[0][1], ac[1][0], ac[1][1]);
        gemm4<16>(Abuf, s0, s1, wsb + 1 * 65536 + wb, ac[0][0], ac[0][1], ac[1][0], ac[1][1]);
        #pragma unroll
        for (int ct = 0; ct < 2; ++ct) {
            const int col = wc * 64 + ct * 32 + l31;
            const float bg = bias[2 * H + col];
            #pragma unroll
            for (int rt = 0; rt < 2; ++rt) {
                float prev = 0.f;
                #pragma unroll
                for (int r = 0; r < 16; ++r) {
                    const float sg = sigm(ac[rt][ct][r] + bg);
                    if ((r & 1) == 0) prev = sg;
                    else ipk[rt][ct][r >> 1] = (unsigned)f2bf(prev) | ((unsigned)f2bf(sg) << 16);
                }
            }
        }
    }
    // ---- gate u (wgb 3, bias 4): c += i * tanh(u) ----
    {
        f32x16 ac[2][2];
        #pragma unroll
        for (int q = 0; q < 2; ++q)
            #pragma unroll
            for (int p = 0; p < 2; ++p)
                #pragma unroll
                for (int r = 0; r < 16; ++r) ac[q][p][r] = 0.f;
        gemm4<24>(Abuf, a0, a1, wgb + 3 * 98304 + wb, ac[0][0], ac[0][1], ac[1][0], ac[1][1]);
        gemm4<16>(Abuf, s0, s1, wsb + 3 * 65536 + wb, ac[0][0], ac[0][1], ac[1][0], ac[1][1]);
        #pragma unroll
        for (int ct = 0; ct < 2; ++ct) {
            const int col = wc * 64 + ct * 32 + l31;
            const float bg = bias[4 * H + col];
            #pragma unroll
            for (int rt = 0; rt < 2; ++rt)
                #pragma unroll
                for (int r = 0; r < 16; ++r) {
                    const float iv = bf2f((unsigned short)((ipk[rt][ct][r >> 1] >> ((r & 1) * 16)) & 0xffffu));
                    cacc[rt][ct][r] += iv * tanh_f(ac[rt][ct][r] + bg);
                }
        }
    }
    // ---- gate o (wgb 4, bias 5): outputs ----
    {
        f32x16 ac[2][2];
        #pragma unroll
        for (int q = 0; q < 2; ++q)
            #pragma unroll
            for (int p = 0; p < 2; ++p)
                #pragma unroll
                for (int r = 0; r < 16; ++r) ac[q][p][r] = 0.f;
        gemm4<24>(Abuf, a0, a1, wgb + 4 * 98304 + wb, ac[0][0], ac[0][1], ac[1][0], ac[1][1]);
        gemm4<16>(Abuf, s0, s1, wsb + 4 * 65536 + wb, ac[0][0], ac[0][1], ac[1][0], ac[1][1]);
        #pragma unroll
        for (int ct = 0; ct < 2; ++ct) {
            const int col = wc * 64 + ct * 32 + l31;
            const float bg = bias[5 * H + col];
            #pragma unroll
            for (int rt = 0; rt < 2; ++rt)
                #pragma unroll
                for (int r = 0; r < 16; ++r) {
                    const int grow = wr * 64 + rt * 32 + (r & 3) + 8 * (r >> 2) + rbase;
                    const size_t idx = (size_t)(b0 + grow) * H + col;
                    const float c = cacc[rt][ct][r];
                    out[idx] = sigm(ac[rt][ct][r] + bg) * tanh_f(c);
                    out[(size_t)Btot * H + idx] = c;
                }
        }
    }
}

extern "C" void kernel_launch(void* const* d_in, const int* in_sizes, int n_in,
                              void* d_out, int out_size, void* d_ws, size_t ws_size,
                              hipStream_t stream) {
    (void)in_sizes; (void)n_in; (void)out_size; (void)ws_size;
    const float* x_t    = (const float*)d_in[0];
    const float* delta  = (const float*)d_in[1];
    const float* h_prev = (const float*)d_in[2];
    const float* c_prev = (const float*)d_in[3];
    const float* Wh     = (const float*)d_in[4];
    const float* Wx     = (const float*)d_in[5];
    const float* Ws     = (const float*)d_in[6];
    const float* Wst    = (const float*)d_in[7];
    const float* bias   = (const float*)d_in[8];
    float* out = (float*)d_out;

    unsigned short* w0  = (unsigned short*)d_ws;   // 98304 bf16
    unsigned short* wgb = w0 + 98304;              // 491520 bf16
    unsigned short* wsb = wgb + 491520;            // 327680 bf16

    const int total = 98304 + 491520 + 327680;     // 917504
    convert_w<<<(total + 255) / 256, 256, 0, stream>>>(Wh, Wx, Ws, w0, wgb, wsb);
    thlstm_fused<<<Btot / BT, NTHR, 0, stream>>>(x_t, delta, h_prev, c_prev,
                                                 Wst, bias, w0, wgb, wsb, out);
}

// Round 7
// 344.947 us; speedup vs baseline: 6.4616x; 6.4616x over previous
//
#include <hip/hip_runtime.h>
#include <hip/hip_bf16.h>

// THLSTM cell fused, MI355X gfx950 — round 7.
// Round-3 structure (the no-spill 345us base: BT=64, 8 waves, 2-acc tile,
// 80KB LDS, K=640 contiguous weights, launch_bounds(512,2)) with deeper
// pipelining: B-ring depth 4, A-ring depth 2 (covers ~250cy L2 latency).

constexpr int Btot = 65536;
constexpr int H    = 256;
constexpr int I    = 128;
constexpr int K1   = 384;   // [h|x]
constexpr int BT   = 64;    // batch rows per WG
constexpr int NTHR = 512;   // 8 waves
constexpr int REG1 = 40960; // LDS region stride (bytes): 32 rows x 80 k8 x 16B

typedef __bf16 bf16x8  __attribute__((ext_vector_type(8)));
typedef float  f32x16  __attribute__((ext_vector_type(16)));
typedef unsigned short ushort8 __attribute__((ext_vector_type(8)));

__device__ __forceinline__ unsigned short f2bf(float f) {
    unsigned u = __builtin_bit_cast(unsigned, f);
    u += 0x7fffu + ((u >> 16) & 1u);   // RNE
    return (unsigned short)(u >> 16);
}
__device__ __forceinline__ float bf2f(unsigned short s) {
    return __builtin_bit_cast(float, ((unsigned)s) << 16);
}
__device__ __forceinline__ float sigm(float x) {
    return __builtin_amdgcn_rcpf(1.0f + exp2f(-1.4426950408889634f * x));
}
__device__ __forceinline__ float tanh_f(float x) {
    return 1.0f - 2.0f * __builtin_amdgcn_rcpf(1.0f + exp2f(2.8853900817779268f * x));
}

// Weights to bf16, layout [k8][col][8]: elem (col, k=k8*8+e) at (k8*256+col)*8+e.
// w0: 48 k8 (K=384), per gate wg: 80 k8 (K=640), 5 gates (f,i,T,u,o).
__global__ void convert_w(const float* __restrict__ Wh, const float* __restrict__ Wx,
                          const float* __restrict__ Ws, unsigned short* __restrict__ w0,
                          unsigned short* __restrict__ wg) {
    const int t  = blockIdx.x * blockDim.x + threadIdx.x;
    const int N0 = 48 * 2048;        // 98304
    const int N1 = 5 * 80 * 2048;    // 819200
    if (t < N0) {
        const int k8 = t >> 11, rem = t & 2047;
        const int col = rem >> 3, e = rem & 7;
        const int k = k8 * 8 + e;
        const float v = (k < H) ? Wh[col * H + k] : Wx[col * I + (k - H)];
        w0[t] = f2bf(v);
    } else if (t < N0 + N1) {
        const int u   = t - N0;
        const int g1  = u / 163840;
        const int rem = u - g1 * 163840;
        const int k8  = rem >> 11;
        const int r2  = rem & 2047;
        const int col = r2 >> 3, e = r2 & 7;
        const int k   = k8 * 8 + e;
        const int g   = g1 + 1;
        float v;
        if (k < H)        v = Wh[g * H * H + col * H + k];
        else if (k < K1)  v = Wx[g * H * I + col * I + (k - H)];
        else              v = Ws[g1 * H * H + col * H + (k - K1)];
        wg[u] = f2bf(v);
    }
}

// K-loop, B-ring depth 4, A-ring depth 2. a-reads lane-linear (conflict-free).
template<int NIT>
__device__ __forceinline__ void gemm_pipe(const unsigned char* Ab, int abase,
        const unsigned short* __restrict__ Wp, f32x16& acc0, f32x16& acc1) {
    bf16x8 b[4], a0[2], a1[2];
    #pragma unroll
    for (int i = 0; i < 4; ++i) b[i] = *(const bf16x8*)(Wp + i * 4096);
    #pragma unroll
    for (int i = 0; i < 2; ++i) {
        a0[i] = *(const bf16x8*)(Ab + abase + i * 1024);
        a1[i] = *(const bf16x8*)(Ab + REG1 + abase + i * 1024);
    }
    #pragma unroll
    for (int i = 0; i < NIT; ++i) {
        const bf16x8 av0 = a0[i & 1], av1 = a1[i & 1], bv = b[i & 3];
        if (i + 2 < NIT) {
            a0[i & 1] = *(const bf16x8*)(Ab + abase + (i + 2) * 1024);
            a1[i & 1] = *(const bf16x8*)(Ab + REG1 + abase + (i + 2) * 1024);
        }
        if (i + 4 < NIT) b[i & 3] = *(const bf16x8*)(Wp + (i + 4) * 4096);
        acc0 = __builtin_amdgcn_mfma_f32_32x32x16_bf16(av0, bv, acc0, 0, 0, 0);
        acc1 = __builtin_amdgcn_mfma_f32_32x32x16_bf16(av1, bv, acc1, 0, 0, 0);
    }
}

__global__ __launch_bounds__(NTHR, 2) void thlstm_fused(
        const float* __restrict__ x_t, const float* __restrict__ delta_t,
        const float* __restrict__ h_prev, const float* __restrict__ c_prev,
        const float* __restrict__ Wst, const float* __restrict__ bias,
        const unsigned short* __restrict__ w0, const unsigned short* __restrict__ wg,
        float* __restrict__ out) {
    __shared__ __align__(16) unsigned char Abuf[BT * 1280];   // 80 KB
    const int tid = threadIdx.x;
    const int b0  = blockIdx.x * BT;

    // ---- stage h|x as bf16, fragment order: chunk(region,row32,k8) ----
    #pragma unroll
    for (int it = 0; it < 6; ++it) {
        const int c   = it * NTHR + tid;
        const int k8  = c >> 6, row = c & 63;
        const float* src = (k8 < 32) ? (h_prev + (size_t)(b0 + row) * H + k8 * 8)
                                     : (x_t    + (size_t)(b0 + row) * I + (k8 - 32) * 8);
        const float4 v0 = ((const float4*)src)[0];
        const float4 v1 = ((const float4*)src)[1];
        ushort8 p;
        p[0] = f2bf(v0.x); p[1] = f2bf(v0.y); p[2] = f2bf(v0.z); p[3] = f2bf(v0.w);
        p[4] = f2bf(v1.x); p[5] = f2bf(v1.y); p[6] = f2bf(v1.z); p[7] = f2bf(v1.w);
        *(ushort8*)(Abuf + (row >> 5) * REG1 + (k8 * 32 + (row & 31)) * 16) = p;
    }
    __syncthreads();

    const int lane  = tid & 63;
    const int wv    = tid >> 6;
    const int half  = lane >> 5;
    const int l31   = lane & 31;
    const int ocol  = wv * 32 + l31;
    const int rbase = 4 * half;
    const int abase = lane * 16;
    const int wlo   = half * 2048 + ocol * 8;
    const int sbase = (48 + (ocol >> 3)) * 512 + (ocol & 7) * 2;  // s slot within region

    // ---- gate s: K=384 ----
    {
        f32x16 acc0, acc1;
        #pragma unroll
        for (int r = 0; r < 16; ++r) { acc0[r] = 0.f; acc1[r] = 0.f; }
        gemm_pipe<24>(Abuf, abase, w0 + wlo, acc0, acc1);
        const float wst = Wst[ocol];
        const float bs  = bias[ocol];
        #pragma unroll
        for (int t = 0; t < 2; ++t)
            #pragma unroll
            for (int r = 0; r < 16; ++r) {
                const int mrow = (r & 3) + 8 * (r >> 2) + rbase;
                const float av = t ? acc1[r] : acc0[r];
                const float pre = av + delta_t[b0 + t * 32 + mrow] * wst + bs;
                *(unsigned short*)(Abuf + t * REG1 + sbase + mrow * 16) = f2bf(tanh_f(pre));
            }
    }
    __syncthreads();

    float    cacc[2][16];
    unsigned ipk[2][8];

    // ---- gate f (wg 0, bias 1): c = f * c_prev ----
    {
        f32x16 ac0, ac1;
        #pragma unroll
        for (int r = 0; r < 16; ++r) { ac0[r] = 0.f; ac1[r] = 0.f; }
        gemm_pipe<40>(Abuf, abase, wg + 0 * 163840 + wlo, ac0, ac1);
        const float bg = bias[1 * H + ocol];
        #pragma unroll
        for (int t = 0; t < 2; ++t)
            #pragma unroll
            for (int r = 0; r < 16; ++r) {
                const int mrow = (r & 3) + 8 * (r >> 2) + rbase;
                const size_t idx = (size_t)(b0 + t * 32 + mrow) * H + ocol;
                const float pre = (t ? ac1[r] : ac0[r]) + bg;
                cacc[t][r] = sigm(pre) * c_prev[idx];
            }
    }
    // ---- gate T (wg 2, bias 3): c += T * s (s from LDS) ----
    {
        f32x16 ac0, ac1;
        #pragma unroll
        for (int r = 0; r < 16; ++r) { ac0[r] = 0.f; ac1[r] = 0.f; }
        gemm_pipe<40>(Abuf, abase, wg + 2 * 163840 + wlo, ac0, ac1);
        const float bg = bias[3 * H + ocol];
        #pragma unroll
        for (int t = 0; t < 2; ++t)
            #pragma unroll
            for (int r = 0; r < 16; ++r) {
                const int mrow = (r & 3) + 8 * (r >> 2) + rbase;
                const float sv = bf2f(*(const unsigned short*)(Abuf + t * REG1 + sbase + mrow * 16));
                const float pre = (t ? ac1[r] : ac0[r]) + bg;
                cacc[t][r] += sigm(pre) * sv;
            }
    }
    // ---- gate i (wg 1, bias 2): keep packed ----
    {
        f32x16 ac0, ac1;
        #pragma unroll
        for (int r = 0; r < 16; ++r) { ac0[r] = 0.f; ac1[r] = 0.f; }
        gemm_pipe<40>(Abuf, abase, wg + 1 * 163840 + wlo, ac0, ac1);
        const float bg = bias[2 * H + ocol];
        #pragma unroll
        for (int t = 0; t < 2; ++t) {
            float tmpf = 0.f;
            #pragma unroll
            for (int r = 0; r < 16; ++r) {
                const float pre = (t ? ac1[r] : ac0[r]) + bg;
                const float sg = sigm(pre);
                if ((r & 1) == 0) tmpf = sg;
                else ipk[t][r >> 1] = (unsigned)f2bf(tmpf) | ((unsigned)f2bf(sg) << 16);
            }
        }
    }
    // ---- gate u (wg 3, bias 4): c += i * tanh(u) ----
    {
        f32x16 ac0, ac1;
        #pragma unroll
        for (int r = 0; r < 16; ++r) { ac0[r] = 0.f; ac1[r] = 0.f; }
        gemm_pipe<40>(Abuf, abase, wg + 3 * 163840 + wlo, ac0, ac1);
        const float bg = bias[4 * H + ocol];
        #pragma unroll
        for (int t = 0; t < 2; ++t)
            #pragma unroll
            for (int r = 0; r < 16; ++r) {
                const float pre = (t ? ac1[r] : ac0[r]) + bg;
                const float iv = bf2f((unsigned short)((ipk[t][r >> 1] >> ((r & 1) * 16)) & 0xffffu));
                cacc[t][r] += iv * tanh_f(pre);
            }
    }
    // ---- gate o (wg 4, bias 5): outputs ----
    {
        f32x16 ac0, ac1;
        #pragma unroll
        for (int r = 0; r < 16; ++r) { ac0[r] = 0.f; ac1[r] = 0.f; }
        gemm_pipe<40>(Abuf, abase, wg + 4 * 163840 + wlo, ac0, ac1);
        const float bg = bias[5 * H + ocol];
        #pragma unroll
        for (int t = 0; t < 2; ++t)
            #pragma unroll
            for (int r = 0; r < 16; ++r) {
                const int mrow = (r & 3) + 8 * (r >> 2) + rbase;
                const size_t idx = (size_t)(b0 + t * 32 + mrow) * H + ocol;
                const float pre = (t ? ac1[r] : ac0[r]) + bg;
                const float c = cacc[t][r];
                out[idx] = sigm(pre) * tanh_f(c);
                out[(size_t)Btot * H + idx] = c;
            }
    }
}

extern "C" void kernel_launch(void* const* d_in, const int* in_sizes, int n_in,
                              void* d_out, int out_size, void* d_ws, size_t ws_size,
                              hipStream_t stream) {
    (void)in_sizes; (void)n_in; (void)out_size; (void)ws_size;
    const float* x_t    = (const float*)d_in[0];
    const float* delta  = (const float*)d_in[1];
    const float* h_prev = (const float*)d_in[2];
    const float* c_prev = (const float*)d_in[3];
    const float* Wh     = (const float*)d_in[4];
    const float* Wx     = (const float*)d_in[5];
    const float* Ws     = (const float*)d_in[6];
    const float* Wst    = (const float*)d_in[7];
    const float* bias   = (const float*)d_in[8];
    float* out = (float*)d_out;

    unsigned short* w0 = (unsigned short*)d_ws;   // 48*2048 bf16
    unsigned short* wg = w0 + 48 * 2048;          // 5*80*2048 bf16

    const int total = 48 * 2048 + 5 * 80 * 2048;  // 917504
    convert_w<<<(total + 255) / 256, 256, 0, stream>>>(Wh, Wx, Ws, w0, wg);
    thlstm_fused<<<Btot / BT, NTHR, 0, stream>>>(x_t, delta, h_prev, c_prev,
                                                 Wst, bias, w0, wg, out);
}